// Round 5
// baseline (1423.847 us; speedup 1.0000x reference)
//
#include <hip/hip_runtime.h>
#include <hip/hip_fp16.h>

#define DIM 64
#define RPB 64             // rows per bucket
#define RPB_SHIFT 6
#define LSTR 68            // LDS row stride (floats): 4 mod 32 banks, 16B aligned
#define HTILE 16384        // edges per block in hist/binpack

// ---------- fallback (round-1) atomic scatter ----------
__global__ __launch_bounds__(256) void scatter_kernel(
    const int* __restrict__ rows, const int* __restrict__ cols,
    const float* __restrict__ vals, const float* __restrict__ feat,
    float* __restrict__ x, int E)
{
    unsigned long long t = (unsigned long long)blockIdx.x * blockDim.x + threadIdx.x;
    int e = (int)(t >> 6);
    int d = (int)(t & 63);
    if (e >= E) return;
    int r = rows[e];
    int c = cols[e];
    float v = vals[e];
    float f = feat[(size_t)c * DIM + d];
    atomicAdd(&x[(size_t)r * DIM + d], v * f);
}

// ---------- feat fp32 -> fp16 table ----------
__global__ __launch_bounds__(256) void cvt_kernel(
    const float* __restrict__ f, __half* __restrict__ h, int n2)
{
    int i = blockIdx.x * blockDim.x + threadIdx.x;
    if (i < n2) {
        float2 v = ((const float2*)f)[i];
        __half2 o;
        o.x = __float2half(v.x);
        o.y = __float2half(v.y);
        ((__half2*)h)[i] = o;
    }
}

// ---------- bucket histogram (LDS-aggregated) ----------
__global__ __launch_bounds__(1024) void hist_kernel(
    const int* __restrict__ rows, int* __restrict__ gcnt, int E, int B)
{
    extern __shared__ int lcnt[];
    for (int i = threadIdx.x; i < B; i += 1024) lcnt[i] = 0;
    __syncthreads();
    int base = blockIdx.x * HTILE;
#pragma unroll
    for (int k = 0; k < HTILE / 1024; ++k) {
        int e = base + k * 1024 + threadIdx.x;
        if (e < E) atomicAdd(&lcnt[rows[e] >> RPB_SHIFT], 1);
    }
    __syncthreads();
    for (int i = threadIdx.x; i < B; i += 1024)
        if (lcnt[i]) atomicAdd(&gcnt[i], lcnt[i]);
}

// ---------- exclusive scan of <=2048 bucket counts, single block ----------
__global__ __launch_bounds__(1024) void scan_kernel(
    const int* __restrict__ gcnt, int* __restrict__ offs,
    int* __restrict__ cursors, int B, int E)
{
    __shared__ int lds[2048];
    int t = threadIdx.x;
    int c0 = (t < B) ? gcnt[t] : 0;
    int c1 = (t + 1024 < B) ? gcnt[t + 1024] : 0;
    lds[t] = c0;
    lds[t + 1024] = c1;
    __syncthreads();
    for (int off = 1; off < 2048; off <<= 1) {
        int a = (t >= off) ? lds[t - off] : 0;
        int b = lds[t + 1024 - off];
        __syncthreads();
        lds[t] += a;
        lds[t + 1024] += b;
        __syncthreads();
    }
    if (t < B)        { offs[t] = lds[t] - c0;               cursors[t] = lds[t] - c0; }
    if (t + 1024 < B) { offs[t + 1024] = lds[t + 1024] - c1; cursors[t + 1024] = lds[t + 1024] - c1; }
    if (t == 0) offs[B] = E;
}

// ---------- bin edges into bucket-sorted order (block-dense writes) ----------
__global__ __launch_bounds__(1024) void binpack_kernel(
    const int* __restrict__ rows, const int* __restrict__ cols,
    const float* __restrict__ vals, int* __restrict__ cursors,
    unsigned long long* __restrict__ sorted, int E, int B)
{
    extern __shared__ int l[];
    int* cnt = l;
    int* bse = l + B;
    for (int i = threadIdx.x; i < B; i += 1024) cnt[i] = 0;
    __syncthreads();
    int tbase = blockIdx.x * HTILE;
#pragma unroll
    for (int k = 0; k < HTILE / 1024; ++k) {
        int e = tbase + k * 1024 + threadIdx.x;
        if (e < E) atomicAdd(&cnt[rows[e] >> RPB_SHIFT], 1);
    }
    __syncthreads();
    for (int i = threadIdx.x; i < B; i += 1024) {
        int c = cnt[i];
        bse[i] = c ? atomicAdd(&cursors[i], c) : 0;
    }
    __syncthreads();
    for (int i = threadIdx.x; i < B; i += 1024) cnt[i] = 0;
    __syncthreads();
#pragma unroll
    for (int k = 0; k < HTILE / 1024; ++k) {
        int e = tbase + k * 1024 + threadIdx.x;
        if (e < E) {
            int r = rows[e];
            int b = r >> RPB_SHIFT;
            int slot = bse[b] + atomicAdd(&cnt[b], 1);
            unsigned long long pk =
                ((unsigned long long)__float_as_uint(vals[e]) << 32) |
                ((unsigned long long)(r & (RPB - 1)) << 17) |
                (unsigned)cols[e];
            sorted[slot] = pk;
        }
    }
}

// ---------- per-bucket LDS accumulate, 8-lane-per-edge ----------
// Lane L serves edge (base + L>>3), dims (L&7)*8..+7.  One dwordx4 per lane
// gathers 8 edges x 128B rows per wave instruction; pk loads are lane-parallel
// vector loads (NOT wave-uniform s_loads -> no lgkmcnt coupling with ds_add).
// Inactive lanes read pk=0 -> v=0.0f -> branchless no-op.
__global__ __launch_bounds__(512) void accumulate_kernel(
    const unsigned long long* __restrict__ sorted, const int* __restrict__ offs,
    const __half* __restrict__ featH, float* __restrict__ x, int N)
{
    __shared__ float ldsx[RPB * LSTR];   // 17.4 KB
    for (int i = threadIdx.x; i < RPB * LSTR; i += 512) ldsx[i] = 0.f;
    __syncthreads();

    int b = blockIdx.x;
    int s = offs[b], t = offs[b + 1];
    int lane = threadIdx.x & 63;
    int wave = threadIdx.x >> 6;        // 0..7
    int eg   = lane >> 3;               // edge-in-group 0..7
    int sub  = lane & 7;                // dim-octet 0..7

    for (int base = s + wave * 16; base < t; base += 8 * 16) {
        int i0 = base + eg;
        int i1 = i0 + 8;
        unsigned long long pk0 = (i0 < t) ? sorted[i0] : 0ull;
        unsigned long long pk1 = (i1 < t) ? sorted[i1] : 0ull;

        unsigned c0 = (unsigned)(pk0 & 0x1FFFFu);
        unsigned c1 = (unsigned)(pk1 & 0x1FFFFu);
        float4 rw0 = *(const float4*)(featH + (size_t)c0 * DIM + sub * 8);
        float4 rw1 = *(const float4*)(featH + (size_t)c1 * DIM + sub * 8);

        int   rl0 = (int)((pk0 >> 17) & (RPB - 1));
        int   rl1 = (int)((pk1 >> 17) & (RPB - 1));
        float v0  = __uint_as_float((unsigned)(pk0 >> 32));
        float v1  = __uint_as_float((unsigned)(pk1 >> 32));

        float f0[8], f1[8];
        {
            __half2 h;
            h = __builtin_bit_cast(__half2, rw0.x); f0[0] = __low2float(h); f0[1] = __high2float(h);
            h = __builtin_bit_cast(__half2, rw0.y); f0[2] = __low2float(h); f0[3] = __high2float(h);
            h = __builtin_bit_cast(__half2, rw0.z); f0[4] = __low2float(h); f0[5] = __high2float(h);
            h = __builtin_bit_cast(__half2, rw0.w); f0[6] = __low2float(h); f0[7] = __high2float(h);
            h = __builtin_bit_cast(__half2, rw1.x); f1[0] = __low2float(h); f1[1] = __high2float(h);
            h = __builtin_bit_cast(__half2, rw1.y); f1[2] = __low2float(h); f1[3] = __high2float(h);
            h = __builtin_bit_cast(__half2, rw1.z); f1[4] = __low2float(h); f1[5] = __high2float(h);
            h = __builtin_bit_cast(__half2, rw1.w); f1[6] = __low2float(h); f1[7] = __high2float(h);
        }
        int a0 = rl0 * LSTR + sub * 8;
        int a1 = rl1 * LSTR + sub * 8;
#pragma unroll
        for (int j = 0; j < 8; ++j)
            atomicAdd(&ldsx[a0 + j], v0 * f0[j]);
#pragma unroll
        for (int j = 0; j < 8; ++j)
            atomicAdd(&ldsx[a1 + j], v1 * f1[j]);
    }
    __syncthreads();

    // write back: 64 rows x 16 float4 (LDS rows are 16B-aligned at stride 68)
    int row0 = b * RPB;
    for (int u = threadIdx.x; u < RPB * (DIM / 4); u += 512) {
        int row = u >> 4;
        int q   = u & 15;
        if (row0 + row < N) {
            float4 vv = *(const float4*)(&ldsx[row * LSTR + q * 4]);
            ((float4*)x)[(size_t)(row0 + row) * (DIM / 4) + q] = vv;
        }
    }
}

// ---------- out = (f+x)@W1 + (f*x)@W2 + (b1+b2) ----------
__global__ __launch_bounds__(256) void transform_kernel(
    const float* __restrict__ feat, const float* __restrict__ x,
    const float* __restrict__ W1, const float* __restrict__ b1,
    const float* __restrict__ W2, const float* __restrict__ b2,
    float* __restrict__ out, int N)
{
    const int lane = threadIdx.x & 63;

    float w1c[DIM], w2c[DIM];
#pragma unroll
    for (int k = 0; k < DIM; ++k) {
        w1c[k] = W1[k * DIM + lane];
        w2c[k] = W2[k * DIM + lane];
    }
    const float bsum = b1[lane] + b2[lane];

    const int wave   = (int)((blockIdx.x * blockDim.x + threadIdx.x) >> 6);
    const int nwaves = (int)((gridDim.x * blockDim.x) >> 6);

    for (int n = wave; n < N; n += nwaves) {
        float f  = feat[n * DIM + lane];
        float xv = x[n * DIM + lane];
        float a = f + xv;
        float b = f * xv;
        float acc = bsum;
#pragma unroll
        for (int k = 0; k < DIM; ++k) {
            float ak = __builtin_bit_cast(float,
                __builtin_amdgcn_readlane(__builtin_bit_cast(int, a), k));
            float bk = __builtin_bit_cast(float,
                __builtin_amdgcn_readlane(__builtin_bit_cast(int, b), k));
            acc = fmaf(ak, w1c[k], acc);
            acc = fmaf(bk, w2c[k], acc);
        }
        out[n * DIM + lane] = acc;
    }
}

extern "C" void kernel_launch(void* const* d_in, const int* in_sizes, int n_in,
                              void* d_out, int out_size, void* d_ws, size_t ws_size,
                              hipStream_t stream)
{
    const int*   rows = (const int*)d_in[0];
    const int*   cols = (const int*)d_in[1];
    const float* vals = (const float*)d_in[2];
    const float* feat = (const float*)d_in[3];
    const float* W1   = (const float*)d_in[4];
    const float* b1   = (const float*)d_in[5];
    const float* W2   = (const float*)d_in[6];
    const float* b2   = (const float*)d_in[7];
    float* out = (float*)d_out;

    const int E = in_sizes[0];
    const int N = in_sizes[3] / DIM;
    const int B = (N + RPB - 1) / RPB;          // buckets

    // workspace layout
    char* ws = (char*)d_ws;
    size_t xBytes     = (size_t)N * DIM * sizeof(float);            // 25.6 MB
    size_t hBytes     = (((size_t)N * DIM * sizeof(__half)) + 255) / 256 * 256; // 12.8 MB
    size_t offsBytes  = (((size_t)(B + 1) * sizeof(int)) + 255) / 256 * 256;
    size_t cursBytes  = (((size_t)B * sizeof(int)) + 255) / 256 * 256;
    size_t sortBytes  = (size_t)E * 8;                              // 25.6 MB

    float*              x       = (float*)ws;
    __half*             featH   = (__half*)(ws + xBytes);
    int*                offs    = (int*)(ws + xBytes + hBytes);
    int*                cursors = (int*)(ws + xBytes + hBytes + offsBytes);
    unsigned long long* sorted  = (unsigned long long*)(ws + xBytes + hBytes + offsBytes + cursBytes);
    size_t need = xBytes + hBytes + offsBytes + cursBytes + sortBytes;

    const int NT = (E + HTILE - 1) / HTILE;     // tiles for hist/binpack

    if (ws_size >= need && B <= 2048 && N <= 131072) {
        cvt_kernel<<<(N * DIM / 2 + 255) / 256, 256, 0, stream>>>(feat, featH, N * DIM / 2);
        hipMemsetAsync(offs, 0, (size_t)(B + 1) * sizeof(int), stream);
        hist_kernel<<<NT, 1024, (size_t)B * 4, stream>>>(rows, offs, E, B);
        scan_kernel<<<1, 1024, 0, stream>>>(offs, offs, cursors, B, E);
        binpack_kernel<<<NT, 1024, (size_t)B * 8, stream>>>(rows, cols, vals,
                                                            cursors, sorted, E, B);
        accumulate_kernel<<<B, 512, 0, stream>>>(sorted, offs, featH, x, N);
    } else {
        hipMemsetAsync(x, 0, xBytes, stream);
        unsigned long long threads = (unsigned long long)E * DIM;
        unsigned int blocks = (unsigned int)((threads + 255ull) / 256ull);
        scatter_kernel<<<blocks, 256, 0, stream>>>(rows, cols, vals, feat, x, E);
    }

    transform_kernel<<<2048, 256, 0, stream>>>(feat, x, W1, b1, W2, b2, out, N);
}

// Round 6
// 325.885 us; speedup vs baseline: 4.3692x; 4.3692x over previous
//
#include <hip/hip_runtime.h>
#include <hip/hip_fp16.h>

#define DIM 64
#define RPB 64             // rows per bucket
#define RPB_SHIFT 6
#define HTILE 16384        // edges per block in hist/binpack

// ---------- fallback (round-1) atomic scatter ----------
__global__ __launch_bounds__(256) void scatter_kernel(
    const int* __restrict__ rows, const int* __restrict__ cols,
    const float* __restrict__ vals, const float* __restrict__ feat,
    float* __restrict__ x, int E)
{
    unsigned long long t = (unsigned long long)blockIdx.x * blockDim.x + threadIdx.x;
    int e = (int)(t >> 6);
    int d = (int)(t & 63);
    if (e >= E) return;
    int r = rows[e];
    int c = cols[e];
    float v = vals[e];
    float f = feat[(size_t)c * DIM + d];
    atomicAdd(&x[(size_t)r * DIM + d], v * f);
}

// ---------- feat fp32 -> fp16 table ----------
__global__ __launch_bounds__(256) void cvt_kernel(
    const float* __restrict__ f, __half* __restrict__ h, int n2)
{
    int i = blockIdx.x * blockDim.x + threadIdx.x;
    if (i < n2) {
        float2 v = ((const float2*)f)[i];
        __half2 o;
        o.x = __float2half(v.x);
        o.y = __float2half(v.y);
        ((__half2*)h)[i] = o;
    }
}

// ---------- bucket histogram (LDS-aggregated) ----------
__global__ __launch_bounds__(1024) void hist_kernel(
    const int* __restrict__ rows, int* __restrict__ gcnt, int E, int B)
{
    extern __shared__ int lcnt[];
    for (int i = threadIdx.x; i < B; i += 1024) lcnt[i] = 0;
    __syncthreads();
    int base = blockIdx.x * HTILE;
#pragma unroll
    for (int k = 0; k < HTILE / 1024; ++k) {
        int e = base + k * 1024 + threadIdx.x;
        if (e < E) atomicAdd(&lcnt[rows[e] >> RPB_SHIFT], 1);
    }
    __syncthreads();
    for (int i = threadIdx.x; i < B; i += 1024)
        if (lcnt[i]) atomicAdd(&gcnt[i], lcnt[i]);
}

// ---------- exclusive scan of <=2048 bucket counts, single block ----------
__global__ __launch_bounds__(1024) void scan_kernel(
    const int* __restrict__ gcnt, int* __restrict__ offs,
    int* __restrict__ cursors, int B, int E)
{
    __shared__ int lds[2048];
    int t = threadIdx.x;
    int c0 = (t < B) ? gcnt[t] : 0;
    int c1 = (t + 1024 < B) ? gcnt[t + 1024] : 0;
    lds[t] = c0;
    lds[t + 1024] = c1;
    __syncthreads();
    for (int off = 1; off < 2048; off <<= 1) {
        int a = (t >= off) ? lds[t - off] : 0;
        int b = lds[t + 1024 - off];
        __syncthreads();
        lds[t] += a;
        lds[t + 1024] += b;
        __syncthreads();
    }
    if (t < B)        { offs[t] = lds[t] - c0;               cursors[t] = lds[t] - c0; }
    if (t + 1024 < B) { offs[t + 1024] = lds[t + 1024] - c1; cursors[t + 1024] = lds[t + 1024] - c1; }
    if (t == 0) offs[B] = E;
}

// ---------- bin edges into bucket-sorted order (block-dense writes) ----------
__global__ __launch_bounds__(1024) void binpack_kernel(
    const int* __restrict__ rows, const int* __restrict__ cols,
    const float* __restrict__ vals, int* __restrict__ cursors,
    unsigned long long* __restrict__ sorted, int E, int B)
{
    extern __shared__ int l[];
    int* cnt = l;
    int* bse = l + B;
    for (int i = threadIdx.x; i < B; i += 1024) cnt[i] = 0;
    __syncthreads();
    int tbase = blockIdx.x * HTILE;
#pragma unroll
    for (int k = 0; k < HTILE / 1024; ++k) {
        int e = tbase + k * 1024 + threadIdx.x;
        if (e < E) atomicAdd(&cnt[rows[e] >> RPB_SHIFT], 1);
    }
    __syncthreads();
    for (int i = threadIdx.x; i < B; i += 1024) {
        int c = cnt[i];
        bse[i] = c ? atomicAdd(&cursors[i], c) : 0;
    }
    __syncthreads();
    for (int i = threadIdx.x; i < B; i += 1024) cnt[i] = 0;
    __syncthreads();
#pragma unroll
    for (int k = 0; k < HTILE / 1024; ++k) {
        int e = tbase + k * 1024 + threadIdx.x;
        if (e < E) {
            int r = rows[e];
            int b = r >> RPB_SHIFT;
            int slot = bse[b] + atomicAdd(&cnt[b], 1);
            unsigned long long pk =
                ((unsigned long long)__float_as_uint(vals[e]) << 32) |
                ((unsigned long long)(r & (RPB - 1)) << 17) |
                (unsigned)cols[e];
            sorted[slot] = pk;
        }
    }
}

// ---------- within-bucket row sort -> full CSR (sorted2 + rowptr) ----------
// One block per bucket. All writes land in the bucket's own contiguous
// window of sorted2 -> no cross-block line sharing, no write amplification.
__global__ __launch_bounds__(1024) void rowsort_kernel(
    const unsigned long long* __restrict__ sorted, const int* __restrict__ offs,
    unsigned long long* __restrict__ sorted2, int* __restrict__ rowptr,
    int N, int E)
{
    __shared__ int rcnt[RPB];
    __shared__ int rbase[RPB];
    int b = blockIdx.x;
    int s = offs[b], t = offs[b + 1];
    int tid = threadIdx.x;
    if (tid < RPB) rcnt[tid] = 0;
    __syncthreads();
    for (int e = s + tid; e < t; e += 1024) {
        int rl = (int)((sorted[e] >> 17) & (RPB - 1));
        atomicAdd(&rcnt[rl], 1);
    }
    __syncthreads();
    if (tid < 64) {          // wave 0: 64-lane prefix scan of row counts
        int lane = tid;
        int c = rcnt[lane];
        int v = c;
        for (int off = 1; off < 64; off <<= 1) {
            int u = __shfl_up(v, off, 64);
            if (lane >= off) v += u;
        }
        int excl = v - c;
        rbase[lane] = excl;
        int row = b * RPB + lane;
        if (row < N) rowptr[row] = s + excl;
        rcnt[lane] = 0;
        if (b == 0 && lane == 0) rowptr[N] = E;
    }
    __syncthreads();
    for (int e = s + tid; e < t; e += 1024) {
        unsigned long long pk = sorted[e];
        int rl = (int)((pk >> 17) & (RPB - 1));
        int idx = atomicAdd(&rcnt[rl], 1);
        sorted2[(size_t)(s + rbase[rl] + idx)] = pk;
    }
}

// ---------- CSR gather-reduce: one wave per row, 8 lanes per edge ----------
// 100K waves (8x the R3-R5 bucket kernels) -> latency hidden by TLP, not
// compiler ILP. Each lane gathers 16B of an edge's fp16 row; per-lane fp32
// octet accumulators; 3-step shfl_xor butterfly combines the 8 edge groups.
__global__ __launch_bounds__(256) void reduce_kernel(
    const unsigned long long* __restrict__ sorted2, const int* __restrict__ rowptr,
    const __half* __restrict__ featH, float* __restrict__ x, int N)
{
    int r = (int)((blockIdx.x * blockDim.x + threadIdx.x) >> 6);
    if (r >= N) return;
    int lane = threadIdx.x & 63;
    int eg  = lane >> 3;     // edge group 0..7
    int sub = lane & 7;      // dim octet 0..7

    int s = rowptr[r], t = rowptr[r + 1];
    float acc[8];
#pragma unroll
    for (int j = 0; j < 8; ++j) acc[j] = 0.f;

    int i = s + eg;
    for (; i + 8 < t; i += 16) {       // 2 edges per lane in flight
        unsigned long long pk0 = sorted2[i];
        unsigned long long pk1 = sorted2[i + 8];
        unsigned c0 = (unsigned)(pk0 & 0x1FFFFu);
        unsigned c1 = (unsigned)(pk1 & 0x1FFFFu);
        float4 rw0 = *(const float4*)(featH + (size_t)c0 * DIM + sub * 8);
        float4 rw1 = *(const float4*)(featH + (size_t)c1 * DIM + sub * 8);
        float v0 = __uint_as_float((unsigned)(pk0 >> 32));
        float v1 = __uint_as_float((unsigned)(pk1 >> 32));
        __half2 h;
        h = __builtin_bit_cast(__half2, rw0.x); acc[0] = fmaf(v0, __low2float(h), acc[0]); acc[1] = fmaf(v0, __high2float(h), acc[1]);
        h = __builtin_bit_cast(__half2, rw0.y); acc[2] = fmaf(v0, __low2float(h), acc[2]); acc[3] = fmaf(v0, __high2float(h), acc[3]);
        h = __builtin_bit_cast(__half2, rw0.z); acc[4] = fmaf(v0, __low2float(h), acc[4]); acc[5] = fmaf(v0, __high2float(h), acc[5]);
        h = __builtin_bit_cast(__half2, rw0.w); acc[6] = fmaf(v0, __low2float(h), acc[6]); acc[7] = fmaf(v0, __high2float(h), acc[7]);
        h = __builtin_bit_cast(__half2, rw1.x); acc[0] = fmaf(v1, __low2float(h), acc[0]); acc[1] = fmaf(v1, __high2float(h), acc[1]);
        h = __builtin_bit_cast(__half2, rw1.y); acc[2] = fmaf(v1, __low2float(h), acc[2]); acc[3] = fmaf(v1, __high2float(h), acc[3]);
        h = __builtin_bit_cast(__half2, rw1.z); acc[4] = fmaf(v1, __low2float(h), acc[4]); acc[5] = fmaf(v1, __high2float(h), acc[5]);
        h = __builtin_bit_cast(__half2, rw1.w); acc[6] = fmaf(v1, __low2float(h), acc[6]); acc[7] = fmaf(v1, __high2float(h), acc[7]);
    }
    if (i < t) {
        unsigned long long pk0 = sorted2[i];
        unsigned c0 = (unsigned)(pk0 & 0x1FFFFu);
        float4 rw0 = *(const float4*)(featH + (size_t)c0 * DIM + sub * 8);
        float v0 = __uint_as_float((unsigned)(pk0 >> 32));
        __half2 h;
        h = __builtin_bit_cast(__half2, rw0.x); acc[0] = fmaf(v0, __low2float(h), acc[0]); acc[1] = fmaf(v0, __high2float(h), acc[1]);
        h = __builtin_bit_cast(__half2, rw0.y); acc[2] = fmaf(v0, __low2float(h), acc[2]); acc[3] = fmaf(v0, __high2float(h), acc[3]);
        h = __builtin_bit_cast(__half2, rw0.z); acc[4] = fmaf(v0, __low2float(h), acc[4]); acc[5] = fmaf(v0, __high2float(h), acc[5]);
        h = __builtin_bit_cast(__half2, rw0.w); acc[6] = fmaf(v0, __low2float(h), acc[6]); acc[7] = fmaf(v0, __high2float(h), acc[7]);
    }

    // butterfly over edge groups: lanes {sub, sub+8, ..., sub+56} combine
#pragma unroll
    for (int off = 8; off < 64; off <<= 1) {
#pragma unroll
        for (int j = 0; j < 8; ++j)
            acc[j] += __shfl_xor(acc[j], off, 64);
    }

    // all lanes now hold the full octet sums; two predicated float4 stores
    if (eg == 0) {
        float4 o; o.x = acc[0]; o.y = acc[1]; o.z = acc[2]; o.w = acc[3];
        *(float4*)(x + (size_t)r * DIM + sub * 8) = o;
    } else if (eg == 1) {
        float4 o; o.x = acc[4]; o.y = acc[5]; o.z = acc[6]; o.w = acc[7];
        *(float4*)(x + (size_t)r * DIM + sub * 8 + 4) = o;
    }
}

// ---------- out = (f+x)@W1 + (f*x)@W2 + (b1+b2) ----------
__global__ __launch_bounds__(256) void transform_kernel(
    const float* __restrict__ feat, const float* __restrict__ x,
    const float* __restrict__ W1, const float* __restrict__ b1,
    const float* __restrict__ W2, const float* __restrict__ b2,
    float* __restrict__ out, int N)
{
    const int lane = threadIdx.x & 63;

    float w1c[DIM], w2c[DIM];
#pragma unroll
    for (int k = 0; k < DIM; ++k) {
        w1c[k] = W1[k * DIM + lane];
        w2c[k] = W2[k * DIM + lane];
    }
    const float bsum = b1[lane] + b2[lane];

    const int wave   = (int)((blockIdx.x * blockDim.x + threadIdx.x) >> 6);
    const int nwaves = (int)((gridDim.x * blockDim.x) >> 6);

    for (int n = wave; n < N; n += nwaves) {
        float f  = feat[n * DIM + lane];
        float xv = x[n * DIM + lane];
        float a = f + xv;
        float b = f * xv;
        float acc = bsum;
#pragma unroll
        for (int k = 0; k < DIM; ++k) {
            float ak = __builtin_bit_cast(float,
                __builtin_amdgcn_readlane(__builtin_bit_cast(int, a), k));
            float bk = __builtin_bit_cast(float,
                __builtin_amdgcn_readlane(__builtin_bit_cast(int, b), k));
            acc = fmaf(ak, w1c[k], acc);
            acc = fmaf(bk, w2c[k], acc);
        }
        out[n * DIM + lane] = acc;
    }
}

extern "C" void kernel_launch(void* const* d_in, const int* in_sizes, int n_in,
                              void* d_out, int out_size, void* d_ws, size_t ws_size,
                              hipStream_t stream)
{
    const int*   rows = (const int*)d_in[0];
    const int*   cols = (const int*)d_in[1];
    const float* vals = (const float*)d_in[2];
    const float* feat = (const float*)d_in[3];
    const float* W1   = (const float*)d_in[4];
    const float* b1   = (const float*)d_in[5];
    const float* W2   = (const float*)d_in[6];
    const float* b2   = (const float*)d_in[7];
    float* out = (float*)d_out;

    const int E = in_sizes[0];
    const int N = in_sizes[3] / DIM;
    const int B = (N + RPB - 1) / RPB;          // buckets

    // workspace layout
    char* ws = (char*)d_ws;
    size_t xBytes     = (size_t)N * DIM * sizeof(float);            // 25.6 MB
    size_t hBytes     = (((size_t)N * DIM * sizeof(__half)) + 255) / 256 * 256; // 12.8 MB
    size_t offsBytes  = (((size_t)(B + 1) * sizeof(int)) + 255) / 256 * 256;
    size_t cursBytes  = (((size_t)B * sizeof(int)) + 255) / 256 * 256;
    size_t rpBytes    = (((size_t)(N + 1) * sizeof(int)) + 255) / 256 * 256;
    size_t sortBytes  = (size_t)E * 8;                              // 25.6 MB

    float*              x       = (float*)ws;
    __half*             featH   = (__half*)(ws + xBytes);
    int*                offs    = (int*)(ws + xBytes + hBytes);
    int*                cursors = (int*)(ws + xBytes + hBytes + offsBytes);
    int*                rowptr  = (int*)(ws + xBytes + hBytes + offsBytes + cursBytes);
    unsigned long long* sorted  = (unsigned long long*)(ws + xBytes + hBytes + offsBytes + cursBytes + rpBytes);
    unsigned long long* sorted2 = sorted + E;
    size_t need = xBytes + hBytes + offsBytes + cursBytes + rpBytes + 2 * sortBytes;

    const int NT = (E + HTILE - 1) / HTILE;     // tiles for hist/binpack

    if (ws_size >= need && B <= 2048 && N <= 131072) {
        cvt_kernel<<<(N * DIM / 2 + 255) / 256, 256, 0, stream>>>(feat, featH, N * DIM / 2);
        hipMemsetAsync(offs, 0, (size_t)(B + 1) * sizeof(int), stream);
        hist_kernel<<<NT, 1024, (size_t)B * 4, stream>>>(rows, offs, E, B);
        scan_kernel<<<1, 1024, 0, stream>>>(offs, offs, cursors, B, E);
        binpack_kernel<<<NT, 1024, (size_t)B * 8, stream>>>(rows, cols, vals,
                                                            cursors, sorted, E, B);
        rowsort_kernel<<<B, 1024, 0, stream>>>(sorted, offs, sorted2, rowptr, N, E);
        reduce_kernel<<<(N + 3) / 4, 256, 0, stream>>>(sorted2, rowptr, featH, x, N);
    } else {
        hipMemsetAsync(x, 0, xBytes, stream);
        unsigned long long threads = (unsigned long long)E * DIM;
        unsigned int blocks = (unsigned int)((threads + 255ull) / 256ull);
        scatter_kernel<<<blocks, 256, 0, stream>>>(rows, cols, vals, feat, x, E);
    }

    transform_kernel<<<2048, 256, 0, stream>>>(feat, x, W1, b1, W2, b2, out, N);
}

// Round 7
// 304.523 us; speedup vs baseline: 4.6757x; 1.0701x over previous
//
#include <hip/hip_runtime.h>
#include <hip/hip_fp16.h>

#define DIM 64
#define RPB 256            // rows per bucket
#define RPB_SHIFT 8
#define HTILE 16384        // edges per block in hist/binpack

// ---------- fallback (round-1) atomic scatter ----------
__global__ __launch_bounds__(256) void scatter_kernel(
    const int* __restrict__ rows, const int* __restrict__ cols,
    const float* __restrict__ vals, const float* __restrict__ feat,
    float* __restrict__ x, int E)
{
    unsigned long long t = (unsigned long long)blockIdx.x * blockDim.x + threadIdx.x;
    int e = (int)(t >> 6);
    int d = (int)(t & 63);
    if (e >= E) return;
    int r = rows[e];
    int c = cols[e];
    float v = vals[e];
    float f = feat[(size_t)c * DIM + d];
    atomicAdd(&x[(size_t)r * DIM + d], v * f);
}

// ---------- feat fp32 -> fp16 table ----------
__global__ __launch_bounds__(256) void cvt_kernel(
    const float* __restrict__ f, __half* __restrict__ h, int n2)
{
    int i = blockIdx.x * blockDim.x + threadIdx.x;
    if (i < n2) {
        float2 v = ((const float2*)f)[i];
        __half2 o;
        o.x = __float2half(v.x);
        o.y = __float2half(v.y);
        ((__half2*)h)[i] = o;
    }
}

// ---------- bucket histogram (LDS-aggregated) ----------
__global__ __launch_bounds__(1024) void hist_kernel(
    const int* __restrict__ rows, int* __restrict__ gcnt, int E, int B)
{
    extern __shared__ int lcnt[];
    for (int i = threadIdx.x; i < B; i += 1024) lcnt[i] = 0;
    __syncthreads();
    int base = blockIdx.x * HTILE;
#pragma unroll
    for (int k = 0; k < HTILE / 1024; ++k) {
        int e = base + k * 1024 + threadIdx.x;
        if (e < E) atomicAdd(&lcnt[rows[e] >> RPB_SHIFT], 1);
    }
    __syncthreads();
    for (int i = threadIdx.x; i < B; i += 1024)
        if (lcnt[i]) atomicAdd(&gcnt[i], lcnt[i]);
}

// ---------- exclusive scan of <=2048 bucket counts, single block ----------
__global__ __launch_bounds__(1024) void scan_kernel(
    const int* __restrict__ gcnt, int* __restrict__ offs,
    int* __restrict__ cursors, int B, int E)
{
    __shared__ int lds[2048];
    int t = threadIdx.x;
    int c0 = (t < B) ? gcnt[t] : 0;
    int c1 = (t + 1024 < B) ? gcnt[t + 1024] : 0;
    lds[t] = c0;
    lds[t + 1024] = c1;
    __syncthreads();
    for (int off = 1; off < 2048; off <<= 1) {
        int a = (t >= off) ? lds[t - off] : 0;
        int b = lds[t + 1024 - off];
        __syncthreads();
        lds[t] += a;
        lds[t + 1024] += b;
        __syncthreads();
    }
    if (t < B)        { offs[t] = lds[t] - c0;               cursors[t] = lds[t] - c0; }
    if (t + 1024 < B) { offs[t + 1024] = lds[t + 1024] - c1; cursors[t + 1024] = lds[t + 1024] - c1; }
    if (t == 0) offs[B] = E;
}

// ---------- bin edges into bucket-sorted order (block-dense writes) ----------
__global__ __launch_bounds__(1024) void binpack_kernel(
    const int* __restrict__ rows, const int* __restrict__ cols,
    const float* __restrict__ vals, int* __restrict__ cursors,
    unsigned long long* __restrict__ sorted, int E, int B)
{
    extern __shared__ int l[];
    int* cnt = l;
    int* bse = l + B;
    for (int i = threadIdx.x; i < B; i += 1024) cnt[i] = 0;
    __syncthreads();
    int tbase = blockIdx.x * HTILE;
#pragma unroll
    for (int k = 0; k < HTILE / 1024; ++k) {
        int e = tbase + k * 1024 + threadIdx.x;
        if (e < E) atomicAdd(&cnt[rows[e] >> RPB_SHIFT], 1);
    }
    __syncthreads();
    for (int i = threadIdx.x; i < B; i += 1024) {
        int c = cnt[i];
        bse[i] = c ? atomicAdd(&cursors[i], c) : 0;
    }
    __syncthreads();
    for (int i = threadIdx.x; i < B; i += 1024) cnt[i] = 0;
    __syncthreads();
#pragma unroll
    for (int k = 0; k < HTILE / 1024; ++k) {
        int e = tbase + k * 1024 + threadIdx.x;
        if (e < E) {
            int r = rows[e];
            int b = r >> RPB_SHIFT;
            int slot = bse[b] + atomicAdd(&cnt[b], 1);
            unsigned long long pk =
                ((unsigned long long)__float_as_uint(vals[e]) << 32) |
                ((unsigned long long)(r & (RPB - 1)) << 17) |
                (unsigned)cols[e];
            sorted[slot] = pk;
        }
    }
}

// ---------- within-bucket row sort -> full CSR (sorted2 + rowptr) ----------
// One block per bucket; all writes land in the bucket's own contiguous
// (block-private, L2-local) window of sorted2 -> no write amplification.
__global__ __launch_bounds__(1024) void rowsort_kernel(
    const unsigned long long* __restrict__ sorted, const int* __restrict__ offs,
    unsigned long long* __restrict__ sorted2, int* __restrict__ rowptr,
    int N, int E)
{
    __shared__ int rcnt[RPB];
    __shared__ int rbase[RPB];
    int b = blockIdx.x;
    int s = offs[b], t = offs[b + 1];
    int tid = threadIdx.x;
    if (tid < RPB) rcnt[tid] = 0;
    __syncthreads();
    for (int e = s + tid; e < t; e += 1024) {
        int rl = (int)((sorted[e] >> 17) & (RPB - 1));
        atomicAdd(&rcnt[rl], 1);
    }
    __syncthreads();
    if (tid < 64) {          // wave 0: scan RPB counts in 64-lane chunks + carry
        int lane = tid;
        int carry = 0;
#pragma unroll
        for (int ch = 0; ch < RPB / 64; ++ch) {
            int idx = ch * 64 + lane;
            int c = rcnt[idx];
            int v = c;
            for (int off = 1; off < 64; off <<= 1) {
                int u = __shfl_up(v, off, 64);
                if (lane >= off) v += u;
            }
            int excl = carry + v - c;
            rbase[idx] = excl;
            int row = b * RPB + idx;
            if (row < N) rowptr[row] = s + excl;
            rcnt[idx] = 0;
            carry += __shfl(v, 63, 64);   // chunk total
        }
        if (b == 0 && lane == 0) rowptr[N] = E;
    }
    __syncthreads();
    for (int e = s + tid; e < t; e += 1024) {
        unsigned long long pk = sorted[e];
        int rl = (int)((pk >> 17) & (RPB - 1));
        int idx = atomicAdd(&rcnt[rl], 1);
        sorted2[(size_t)(s + rbase[rl] + idx)] = pk;
    }
}

// ---------- CSR gather-reduce: one wave per row, 8 lanes per edge ----------
__global__ __launch_bounds__(256) void reduce_kernel(
    const unsigned long long* __restrict__ sorted2, const int* __restrict__ rowptr,
    const __half* __restrict__ featH, float* __restrict__ x, int N)
{
    int r = (int)((blockIdx.x * blockDim.x + threadIdx.x) >> 6);
    if (r >= N) return;
    int lane = threadIdx.x & 63;
    int eg  = lane >> 3;     // edge group 0..7
    int sub = lane & 7;      // dim octet 0..7

    int s = rowptr[r], t = rowptr[r + 1];
    float acc[8];
#pragma unroll
    for (int j = 0; j < 8; ++j) acc[j] = 0.f;

    int i = s + eg;
    for (; i + 8 < t; i += 16) {       // 2 edges per lane in flight
        unsigned long long pk0 = sorted2[i];
        unsigned long long pk1 = sorted2[i + 8];
        unsigned c0 = (unsigned)(pk0 & 0x1FFFFu);
        unsigned c1 = (unsigned)(pk1 & 0x1FFFFu);
        float4 rw0 = *(const float4*)(featH + (size_t)c0 * DIM + sub * 8);
        float4 rw1 = *(const float4*)(featH + (size_t)c1 * DIM + sub * 8);
        float v0 = __uint_as_float((unsigned)(pk0 >> 32));
        float v1 = __uint_as_float((unsigned)(pk1 >> 32));
        __half2 h;
        h = __builtin_bit_cast(__half2, rw0.x); acc[0] = fmaf(v0, __low2float(h), acc[0]); acc[1] = fmaf(v0, __high2float(h), acc[1]);
        h = __builtin_bit_cast(__half2, rw0.y); acc[2] = fmaf(v0, __low2float(h), acc[2]); acc[3] = fmaf(v0, __high2float(h), acc[3]);
        h = __builtin_bit_cast(__half2, rw0.z); acc[4] = fmaf(v0, __low2float(h), acc[4]); acc[5] = fmaf(v0, __high2float(h), acc[5]);
        h = __builtin_bit_cast(__half2, rw0.w); acc[6] = fmaf(v0, __low2float(h), acc[6]); acc[7] = fmaf(v0, __high2float(h), acc[7]);
        h = __builtin_bit_cast(__half2, rw1.x); acc[0] = fmaf(v1, __low2float(h), acc[0]); acc[1] = fmaf(v1, __high2float(h), acc[1]);
        h = __builtin_bit_cast(__half2, rw1.y); acc[2] = fmaf(v1, __low2float(h), acc[2]); acc[3] = fmaf(v1, __high2float(h), acc[3]);
        h = __builtin_bit_cast(__half2, rw1.z); acc[4] = fmaf(v1, __low2float(h), acc[4]); acc[5] = fmaf(v1, __high2float(h), acc[5]);
        h = __builtin_bit_cast(__half2, rw1.w); acc[6] = fmaf(v1, __low2float(h), acc[6]); acc[7] = fmaf(v1, __high2float(h), acc[7]);
    }
    if (i < t) {
        unsigned long long pk0 = sorted2[i];
        unsigned c0 = (unsigned)(pk0 & 0x1FFFFu);
        float4 rw0 = *(const float4*)(featH + (size_t)c0 * DIM + sub * 8);
        float v0 = __uint_as_float((unsigned)(pk0 >> 32));
        __half2 h;
        h = __builtin_bit_cast(__half2, rw0.x); acc[0] = fmaf(v0, __low2float(h), acc[0]); acc[1] = fmaf(v0, __high2float(h), acc[1]);
        h = __builtin_bit_cast(__half2, rw0.y); acc[2] = fmaf(v0, __low2float(h), acc[2]); acc[3] = fmaf(v0, __high2float(h), acc[3]);
        h = __builtin_bit_cast(__half2, rw0.z); acc[4] = fmaf(v0, __low2float(h), acc[4]); acc[5] = fmaf(v0, __high2float(h), acc[5]);
        h = __builtin_bit_cast(__half2, rw0.w); acc[6] = fmaf(v0, __low2float(h), acc[6]); acc[7] = fmaf(v0, __high2float(h), acc[7]);
    }

#pragma unroll
    for (int off = 8; off < 64; off <<= 1) {
#pragma unroll
        for (int j = 0; j < 8; ++j)
            acc[j] += __shfl_xor(acc[j], off, 64);
    }

    if (eg == 0) {
        float4 o; o.x = acc[0]; o.y = acc[1]; o.z = acc[2]; o.w = acc[3];
        *(float4*)(x + (size_t)r * DIM + sub * 8) = o;
    } else if (eg == 1) {
        float4 o; o.x = acc[4]; o.y = acc[5]; o.z = acc[6]; o.w = acc[7];
        *(float4*)(x + (size_t)r * DIM + sub * 8 + 4) = o;
    }
}

// ---------- out = (f+x)@W1 + (f*x)@W2 + (b1+b2) ----------
__global__ __launch_bounds__(256) void transform_kernel(
    const float* __restrict__ feat, const float* __restrict__ x,
    const float* __restrict__ W1, const float* __restrict__ b1,
    const float* __restrict__ W2, const float* __restrict__ b2,
    float* __restrict__ out, int N)
{
    const int lane = threadIdx.x & 63;

    float w1c[DIM], w2c[DIM];
#pragma unroll
    for (int k = 0; k < DIM; ++k) {
        w1c[k] = W1[k * DIM + lane];
        w2c[k] = W2[k * DIM + lane];
    }
    const float bsum = b1[lane] + b2[lane];

    const int wave   = (int)((blockIdx.x * blockDim.x + threadIdx.x) >> 6);
    const int nwaves = (int)((gridDim.x * blockDim.x) >> 6);

    for (int n = wave; n < N; n += nwaves) {
        float f  = feat[n * DIM + lane];
        float xv = x[n * DIM + lane];
        float a = f + xv;
        float b = f * xv;
        float acc = bsum;
#pragma unroll
        for (int k = 0; k < DIM; ++k) {
            float ak = __builtin_bit_cast(float,
                __builtin_amdgcn_readlane(__builtin_bit_cast(int, a), k));
            float bk = __builtin_bit_cast(float,
                __builtin_amdgcn_readlane(__builtin_bit_cast(int, b), k));
            acc = fmaf(ak, w1c[k], acc);
            acc = fmaf(bk, w2c[k], acc);
        }
        out[n * DIM + lane] = acc;
    }
}

extern "C" void kernel_launch(void* const* d_in, const int* in_sizes, int n_in,
                              void* d_out, int out_size, void* d_ws, size_t ws_size,
                              hipStream_t stream)
{
    const int*   rows = (const int*)d_in[0];
    const int*   cols = (const int*)d_in[1];
    const float* vals = (const float*)d_in[2];
    const float* feat = (const float*)d_in[3];
    const float* W1   = (const float*)d_in[4];
    const float* b1   = (const float*)d_in[5];
    const float* W2   = (const float*)d_in[6];
    const float* b2   = (const float*)d_in[7];
    float* out = (float*)d_out;

    const int E = in_sizes[0];
    const int N = in_sizes[3] / DIM;
    const int B = (N + RPB - 1) / RPB;          // buckets

    // workspace layout
    char* ws = (char*)d_ws;
    size_t xBytes     = (size_t)N * DIM * sizeof(float);            // 25.6 MB
    size_t hBytes     = (((size_t)N * DIM * sizeof(__half)) + 255) / 256 * 256; // 12.8 MB
    size_t offsBytes  = (((size_t)(B + 1) * sizeof(int)) + 255) / 256 * 256;
    size_t cursBytes  = (((size_t)B * sizeof(int)) + 255) / 256 * 256;
    size_t rpBytes    = (((size_t)(N + 1) * sizeof(int)) + 255) / 256 * 256;
    size_t sortBytes  = (size_t)E * 8;                              // 25.6 MB

    float*              x       = (float*)ws;
    __half*             featH   = (__half*)(ws + xBytes);
    int*                offs    = (int*)(ws + xBytes + hBytes);
    int*                cursors = (int*)(ws + xBytes + hBytes + offsBytes);
    int*                rowptr  = (int*)(ws + xBytes + hBytes + offsBytes + cursBytes);
    unsigned long long* sorted  = (unsigned long long*)(ws + xBytes + hBytes + offsBytes + cursBytes + rpBytes);
    unsigned long long* sorted2 = sorted + E;
    size_t need = xBytes + hBytes + offsBytes + cursBytes + rpBytes + 2 * sortBytes;

    const int NT = (E + HTILE - 1) / HTILE;     // tiles for hist/binpack

    if (ws_size >= need && B <= 2048 && N <= 131072) {
        cvt_kernel<<<(N * DIM / 2 + 255) / 256, 256, 0, stream>>>(feat, featH, N * DIM / 2);
        hipMemsetAsync(offs, 0, (size_t)(B + 1) * sizeof(int), stream);
        hist_kernel<<<NT, 1024, (size_t)B * 4, stream>>>(rows, offs, E, B);
        scan_kernel<<<1, 1024, 0, stream>>>(offs, offs, cursors, B, E);
        binpack_kernel<<<NT, 1024, (size_t)B * 8, stream>>>(rows, cols, vals,
                                                            cursors, sorted, E, B);
        rowsort_kernel<<<B, 1024, 0, stream>>>(sorted, offs, sorted2, rowptr, N, E);
        reduce_kernel<<<(N + 3) / 4, 256, 0, stream>>>(sorted2, rowptr, featH, x, N);
    } else {
        hipMemsetAsync(x, 0, xBytes, stream);
        unsigned long long threads = (unsigned long long)E * DIM;
        unsigned int blocks = (unsigned int)((threads + 255ull) / 256ull);
        scatter_kernel<<<blocks, 256, 0, stream>>>(rows, cols, vals, feat, x, E);
    }

    transform_kernel<<<2048, 256, 0, stream>>>(feat, x, W1, b1, W2, b2, out, N);
}

// Round 8
// 275.142 us; speedup vs baseline: 5.1750x; 1.1068x over previous
//
#include <hip/hip_runtime.h>
#include <hip/hip_fp16.h>

#define DIM 64
#define RPB 256            // rows per bucket
#define RPB_SHIFT 8
#define HTILE 16384        // edges per block in hist/binpack

typedef _Float16 half8 __attribute__((ext_vector_type(8)));
typedef float    f32x4 __attribute__((ext_vector_type(4)));

// ---------- fallback (round-1) atomic scatter ----------
__global__ __launch_bounds__(256) void scatter_kernel(
    const int* __restrict__ rows, const int* __restrict__ cols,
    const float* __restrict__ vals, const float* __restrict__ feat,
    float* __restrict__ x, int E)
{
    unsigned long long t = (unsigned long long)blockIdx.x * blockDim.x + threadIdx.x;
    int e = (int)(t >> 6);
    int d = (int)(t & 63);
    if (e >= E) return;
    int r = rows[e];
    int c = cols[e];
    float v = vals[e];
    float f = feat[(size_t)c * DIM + d];
    atomicAdd(&x[(size_t)r * DIM + d], v * f);
}

// ---------- feat fp32 -> fp16 table ----------
__global__ __launch_bounds__(256) void cvt_kernel(
    const float* __restrict__ f, __half* __restrict__ h, int n2)
{
    int i = blockIdx.x * blockDim.x + threadIdx.x;
    if (i < n2) {
        float2 v = ((const float2*)f)[i];
        __half2 o;
        o.x = __float2half(v.x);
        o.y = __float2half(v.y);
        ((__half2*)h)[i] = o;
    }
}

// ---------- bucket histogram (LDS-aggregated) ----------
__global__ __launch_bounds__(1024) void hist_kernel(
    const int* __restrict__ rows, int* __restrict__ gcnt, int E, int B)
{
    extern __shared__ int lcnt[];
    for (int i = threadIdx.x; i < B; i += 1024) lcnt[i] = 0;
    __syncthreads();
    int base = blockIdx.x * HTILE;
#pragma unroll
    for (int k = 0; k < HTILE / 1024; ++k) {
        int e = base + k * 1024 + threadIdx.x;
        if (e < E) atomicAdd(&lcnt[rows[e] >> RPB_SHIFT], 1);
    }
    __syncthreads();
    for (int i = threadIdx.x; i < B; i += 1024)
        if (lcnt[i]) atomicAdd(&gcnt[i], lcnt[i]);
}

// ---------- exclusive scan of <=2048 bucket counts, single block ----------
__global__ __launch_bounds__(1024) void scan_kernel(
    const int* __restrict__ gcnt, int* __restrict__ offs,
    int* __restrict__ cursors, int B, int E)
{
    __shared__ int lds[2048];
    int t = threadIdx.x;
    int c0 = (t < B) ? gcnt[t] : 0;
    int c1 = (t + 1024 < B) ? gcnt[t + 1024] : 0;
    lds[t] = c0;
    lds[t + 1024] = c1;
    __syncthreads();
    for (int off = 1; off < 2048; off <<= 1) {
        int a = (t >= off) ? lds[t - off] : 0;
        int b = lds[t + 1024 - off];
        __syncthreads();
        lds[t] += a;
        lds[t + 1024] += b;
        __syncthreads();
    }
    if (t < B)        { offs[t] = lds[t] - c0;               cursors[t] = lds[t] - c0; }
    if (t + 1024 < B) { offs[t + 1024] = lds[t + 1024] - c1; cursors[t + 1024] = lds[t + 1024] - c1; }
    if (t == 0) offs[B] = E;
}

// ---------- bin edges into bucket-sorted order (block-dense writes) ----------
__global__ __launch_bounds__(1024) void binpack_kernel(
    const int* __restrict__ rows, const int* __restrict__ cols,
    const float* __restrict__ vals, int* __restrict__ cursors,
    unsigned long long* __restrict__ sorted, int E, int B)
{
    extern __shared__ int l[];
    int* cnt = l;
    int* bse = l + B;
    for (int i = threadIdx.x; i < B; i += 1024) cnt[i] = 0;
    __syncthreads();
    int tbase = blockIdx.x * HTILE;
#pragma unroll
    for (int k = 0; k < HTILE / 1024; ++k) {
        int e = tbase + k * 1024 + threadIdx.x;
        if (e < E) atomicAdd(&cnt[rows[e] >> RPB_SHIFT], 1);
    }
    __syncthreads();
    for (int i = threadIdx.x; i < B; i += 1024) {
        int c = cnt[i];
        bse[i] = c ? atomicAdd(&cursors[i], c) : 0;
    }
    __syncthreads();
    for (int i = threadIdx.x; i < B; i += 1024) cnt[i] = 0;
    __syncthreads();
#pragma unroll
    for (int k = 0; k < HTILE / 1024; ++k) {
        int e = tbase + k * 1024 + threadIdx.x;
        if (e < E) {
            int r = rows[e];
            int b = r >> RPB_SHIFT;
            int slot = bse[b] + atomicAdd(&cnt[b], 1);
            unsigned long long pk =
                ((unsigned long long)__float_as_uint(vals[e]) << 32) |
                ((unsigned long long)(r & (RPB - 1)) << 17) |
                (unsigned)cols[e];
            sorted[slot] = pk;
        }
    }
}

// ---------- within-bucket row sort -> full CSR (sorted2 + rowptr) ----------
__global__ __launch_bounds__(1024) void rowsort_kernel(
    const unsigned long long* __restrict__ sorted, const int* __restrict__ offs,
    unsigned long long* __restrict__ sorted2, int* __restrict__ rowptr,
    int N, int E)
{
    __shared__ int rcnt[RPB];
    __shared__ int rbase[RPB];
    int b = blockIdx.x;
    int s = offs[b], t = offs[b + 1];
    int tid = threadIdx.x;
    if (tid < RPB) rcnt[tid] = 0;
    __syncthreads();
    for (int e = s + tid; e < t; e += 1024) {
        int rl = (int)((sorted[e] >> 17) & (RPB - 1));
        atomicAdd(&rcnt[rl], 1);
    }
    __syncthreads();
    if (tid < 64) {          // wave 0: scan RPB counts in 64-lane chunks + carry
        int lane = tid;
        int carry = 0;
#pragma unroll
        for (int ch = 0; ch < RPB / 64; ++ch) {
            int idx = ch * 64 + lane;
            int c = rcnt[idx];
            int v = c;
            for (int off = 1; off < 64; off <<= 1) {
                int u = __shfl_up(v, off, 64);
                if (lane >= off) v += u;
            }
            int excl = carry + v - c;
            rbase[idx] = excl;
            int row = b * RPB + idx;
            if (row < N) rowptr[row] = s + excl;
            rcnt[idx] = 0;
            carry += __shfl(v, 63, 64);   // chunk total
        }
        if (b == 0 && lane == 0) rowptr[N] = E;
    }
    __syncthreads();
    for (int e = s + tid; e < t; e += 1024) {
        unsigned long long pk = sorted[e];
        int rl = (int)((pk >> 17) & (RPB - 1));
        int idx = atomicAdd(&rcnt[rl], 1);
        sorted2[(size_t)(s + rbase[rl] + idx)] = pk;
    }
}

// ---------- CSR gather-reduce: one wave per row, 8 lanes per edge ----------
__global__ __launch_bounds__(256) void reduce_kernel(
    const unsigned long long* __restrict__ sorted2, const int* __restrict__ rowptr,
    const __half* __restrict__ featH, float* __restrict__ x, int N)
{
    int r = (int)((blockIdx.x * blockDim.x + threadIdx.x) >> 6);
    if (r >= N) return;
    int lane = threadIdx.x & 63;
    int eg  = lane >> 3;     // edge group 0..7
    int sub = lane & 7;      // dim octet 0..7

    int s = rowptr[r], t = rowptr[r + 1];
    float acc[8];
#pragma unroll
    for (int j = 0; j < 8; ++j) acc[j] = 0.f;

    int i = s + eg;
    for (; i + 8 < t; i += 16) {       // 2 edges per lane in flight
        unsigned long long pk0 = sorted2[i];
        unsigned long long pk1 = sorted2[i + 8];
        unsigned c0 = (unsigned)(pk0 & 0x1FFFFu);
        unsigned c1 = (unsigned)(pk1 & 0x1FFFFu);
        float4 rw0 = *(const float4*)(featH + (size_t)c0 * DIM + sub * 8);
        float4 rw1 = *(const float4*)(featH + (size_t)c1 * DIM + sub * 8);
        float v0 = __uint_as_float((unsigned)(pk0 >> 32));
        float v1 = __uint_as_float((unsigned)(pk1 >> 32));
        __half2 h;
        h = __builtin_bit_cast(__half2, rw0.x); acc[0] = fmaf(v0, __low2float(h), acc[0]); acc[1] = fmaf(v0, __high2float(h), acc[1]);
        h = __builtin_bit_cast(__half2, rw0.y); acc[2] = fmaf(v0, __low2float(h), acc[2]); acc[3] = fmaf(v0, __high2float(h), acc[3]);
        h = __builtin_bit_cast(__half2, rw0.z); acc[4] = fmaf(v0, __low2float(h), acc[4]); acc[5] = fmaf(v0, __high2float(h), acc[5]);
        h = __builtin_bit_cast(__half2, rw0.w); acc[6] = fmaf(v0, __low2float(h), acc[6]); acc[7] = fmaf(v0, __high2float(h), acc[7]);
        h = __builtin_bit_cast(__half2, rw1.x); acc[0] = fmaf(v1, __low2float(h), acc[0]); acc[1] = fmaf(v1, __high2float(h), acc[1]);
        h = __builtin_bit_cast(__half2, rw1.y); acc[2] = fmaf(v1, __low2float(h), acc[2]); acc[3] = fmaf(v1, __high2float(h), acc[3]);
        h = __builtin_bit_cast(__half2, rw1.z); acc[4] = fmaf(v1, __low2float(h), acc[4]); acc[5] = fmaf(v1, __high2float(h), acc[5]);
        h = __builtin_bit_cast(__half2, rw1.w); acc[6] = fmaf(v1, __low2float(h), acc[6]); acc[7] = fmaf(v1, __high2float(h), acc[7]);
    }
    if (i < t) {
        unsigned long long pk0 = sorted2[i];
        unsigned c0 = (unsigned)(pk0 & 0x1FFFFu);
        float4 rw0 = *(const float4*)(featH + (size_t)c0 * DIM + sub * 8);
        float v0 = __uint_as_float((unsigned)(pk0 >> 32));
        __half2 h;
        h = __builtin_bit_cast(__half2, rw0.x); acc[0] = fmaf(v0, __low2float(h), acc[0]); acc[1] = fmaf(v0, __high2float(h), acc[1]);
        h = __builtin_bit_cast(__half2, rw0.y); acc[2] = fmaf(v0, __low2float(h), acc[2]); acc[3] = fmaf(v0, __high2float(h), acc[3]);
        h = __builtin_bit_cast(__half2, rw0.z); acc[4] = fmaf(v0, __low2float(h), acc[4]); acc[5] = fmaf(v0, __high2float(h), acc[5]);
        h = __builtin_bit_cast(__half2, rw0.w); acc[6] = fmaf(v0, __low2float(h), acc[6]); acc[7] = fmaf(v0, __high2float(h), acc[7]);
    }

#pragma unroll
    for (int off = 8; off < 64; off <<= 1) {
#pragma unroll
        for (int j = 0; j < 8; ++j)
            acc[j] += __shfl_xor(acc[j], off, 64);
    }

    if (eg == 0) {
        float4 o; o.x = acc[0]; o.y = acc[1]; o.z = acc[2]; o.w = acc[3];
        *(float4*)(x + (size_t)r * DIM + sub * 8) = o;
    } else if (eg == 1) {
        float4 o; o.x = acc[4]; o.y = acc[5]; o.z = acc[6]; o.w = acc[7];
        *(float4*)(x + (size_t)r * DIM + sub * 8 + 4) = o;
    }
}

// ---------- MFMA transform: out = [a|b] @ [W1;W2] + (b1+b2) ----------
// a = f+x, b = f*x.  M=N nodes, K=128, N=64.  Wave computes a 16-row tile:
// 4 col-tiles x 4 k-steps of v_mfma_f32_16x16x32_f16.
// A-frag: lane holds A[m=lane&15][k=quad*8+j]; B-frag: B[k=quad*8+j][n=lane&15];
// C/D: col=lane&15, row=quad*4+reg.  W frags (64 VGPRs) loaded once per wave.
__global__ __launch_bounds__(256) void transform_mfma_kernel(
    const float* __restrict__ feat, const float* __restrict__ x,
    const float* __restrict__ W1, const float* __restrict__ b1,
    const float* __restrict__ W2, const float* __restrict__ b2,
    float* __restrict__ out, int N)
{
    const int lane = threadIdx.x & 63;
    const int m    = lane & 15;
    const int quad = lane >> 4;

    // W fragments: wfrag[t][c]; t: 0=W1 k0..31, 1=W1 k32..63, 2=W2 k0..31, 3=W2 k32..63
    half8 wfrag[4][4];
#pragma unroll
    for (int t = 0; t < 4; ++t) {
        const float* Wsrc = (t < 2) ? W1 : W2;
        int kbase = (t & 1) * 32 + quad * 8;
#pragma unroll
        for (int c = 0; c < 4; ++c) {
            int col = c * 16 + m;
            half8 w;
#pragma unroll
            for (int j = 0; j < 8; ++j)
                w[j] = (_Float16)Wsrc[(kbase + j) * DIM + col];
            wfrag[t][c] = w;
        }
    }
    float bias[4];
#pragma unroll
    for (int c = 0; c < 4; ++c)
        bias[c] = b1[c * 16 + m] + b2[c * 16 + m];

    const int ntiles = (N + 15) / 16;
    const int wid    = (int)((blockIdx.x * blockDim.x + threadIdx.x) >> 6);
    const int nwaves = (int)((gridDim.x * blockDim.x) >> 6);

    for (int tile = wid; tile < ntiles; tile += nwaves) {
        int row  = tile * 16 + m;
        int rldr = (row < N) ? row : (N - 1);
        const float* fp = feat + (size_t)rldr * DIM + quad * 8;
        const float* xp = x    + (size_t)rldr * DIM + quad * 8;
        float4 fl0 = *(const float4*)(fp);
        float4 fl1 = *(const float4*)(fp + 4);
        float4 fh0 = *(const float4*)(fp + 32);
        float4 fh1 = *(const float4*)(fp + 36);
        float4 xl0 = *(const float4*)(xp);
        float4 xl1 = *(const float4*)(xp + 4);
        float4 xh0 = *(const float4*)(xp + 32);
        float4 xh1 = *(const float4*)(xp + 36);

        half8 alo, ahi, blo, bhi;
        alo[0] = (_Float16)(fl0.x + xl0.x); blo[0] = (_Float16)(fl0.x * xl0.x);
        alo[1] = (_Float16)(fl0.y + xl0.y); blo[1] = (_Float16)(fl0.y * xl0.y);
        alo[2] = (_Float16)(fl0.z + xl0.z); blo[2] = (_Float16)(fl0.z * xl0.z);
        alo[3] = (_Float16)(fl0.w + xl0.w); blo[3] = (_Float16)(fl0.w * xl0.w);
        alo[4] = (_Float16)(fl1.x + xl1.x); blo[4] = (_Float16)(fl1.x * xl1.x);
        alo[5] = (_Float16)(fl1.y + xl1.y); blo[5] = (_Float16)(fl1.y * xl1.y);
        alo[6] = (_Float16)(fl1.z + xl1.z); blo[6] = (_Float16)(fl1.z * xl1.z);
        alo[7] = (_Float16)(fl1.w + xl1.w); blo[7] = (_Float16)(fl1.w * xl1.w);
        ahi[0] = (_Float16)(fh0.x + xh0.x); bhi[0] = (_Float16)(fh0.x * xh0.x);
        ahi[1] = (_Float16)(fh0.y + xh0.y); bhi[1] = (_Float16)(fh0.y * xh0.y);
        ahi[2] = (_Float16)(fh0.z + xh0.z); bhi[2] = (_Float16)(fh0.z * xh0.z);
        ahi[3] = (_Float16)(fh0.w + xh0.w); bhi[3] = (_Float16)(fh0.w * xh0.w);
        ahi[4] = (_Float16)(fh1.x + xh1.x); bhi[4] = (_Float16)(fh1.x * xh1.x);
        ahi[5] = (_Float16)(fh1.y + xh1.y); bhi[5] = (_Float16)(fh1.y * xh1.y);
        ahi[6] = (_Float16)(fh1.z + xh1.z); bhi[6] = (_Float16)(fh1.z * xh1.z);
        ahi[7] = (_Float16)(fh1.w + xh1.w); bhi[7] = (_Float16)(fh1.w * xh1.w);

        f32x4 acc[4];
#pragma unroll
        for (int c = 0; c < 4; ++c) {
            f32x4 a0 = { bias[c], bias[c], bias[c], bias[c] };
            a0 = __builtin_amdgcn_mfma_f32_16x16x32_f16(alo, wfrag[0][c], a0, 0, 0, 0);
            a0 = __builtin_amdgcn_mfma_f32_16x16x32_f16(ahi, wfrag[1][c], a0, 0, 0, 0);
            a0 = __builtin_amdgcn_mfma_f32_16x16x32_f16(blo, wfrag[2][c], a0, 0, 0, 0);
            a0 = __builtin_amdgcn_mfma_f32_16x16x32_f16(bhi, wfrag[3][c], a0, 0, 0, 0);
            acc[c] = a0;
        }

#pragma unroll
        for (int reg = 0; reg < 4; ++reg) {
            int orow = tile * 16 + quad * 4 + reg;
            if (orow < N) {
#pragma unroll
                for (int c = 0; c < 4; ++c)
                    out[(size_t)orow * DIM + c * 16 + m] = acc[c][reg];
            }
        }
    }
}

extern "C" void kernel_launch(void* const* d_in, const int* in_sizes, int n_in,
                              void* d_out, int out_size, void* d_ws, size_t ws_size,
                              hipStream_t stream)
{
    const int*   rows = (const int*)d_in[0];
    const int*   cols = (const int*)d_in[1];
    const float* vals = (const float*)d_in[2];
    const float* feat = (const float*)d_in[3];
    const float* W1   = (const float*)d_in[4];
    const float* b1   = (const float*)d_in[5];
    const float* W2   = (const float*)d_in[6];
    const float* b2   = (const float*)d_in[7];
    float* out = (float*)d_out;

    const int E = in_sizes[0];
    const int N = in_sizes[3] / DIM;
    const int B = (N + RPB - 1) / RPB;          // buckets

    // workspace layout
    char* ws = (char*)d_ws;
    size_t xBytes     = (size_t)N * DIM * sizeof(float);            // 25.6 MB
    size_t hBytes     = (((size_t)N * DIM * sizeof(__half)) + 255) / 256 * 256; // 12.8 MB
    size_t offsBytes  = (((size_t)(B + 1) * sizeof(int)) + 255) / 256 * 256;
    size_t cursBytes  = (((size_t)B * sizeof(int)) + 255) / 256 * 256;
    size_t rpBytes    = (((size_t)(N + 1) * sizeof(int)) + 255) / 256 * 256;
    size_t sortBytes  = (size_t)E * 8;                              // 25.6 MB

    float*              x       = (float*)ws;
    __half*             featH   = (__half*)(ws + xBytes);
    int*                offs    = (int*)(ws + xBytes + hBytes);
    int*                cursors = (int*)(ws + xBytes + hBytes + offsBytes);
    int*                rowptr  = (int*)(ws + xBytes + hBytes + offsBytes + cursBytes);
    unsigned long long* sorted  = (unsigned long long*)(ws + xBytes + hBytes + offsBytes + cursBytes + rpBytes);
    unsigned long long* sorted2 = sorted + E;
    size_t need = xBytes + hBytes + offsBytes + cursBytes + rpBytes + 2 * sortBytes;

    const int NT = (E + HTILE - 1) / HTILE;     // tiles for hist/binpack

    if (ws_size >= need && B <= 2048 && N <= 131072) {
        cvt_kernel<<<(N * DIM / 2 + 255) / 256, 256, 0, stream>>>(feat, featH, N * DIM / 2);
        hipMemsetAsync(offs, 0, (size_t)(B + 1) * sizeof(int), stream);
        hist_kernel<<<NT, 1024, (size_t)B * 4, stream>>>(rows, offs, E, B);
        scan_kernel<<<1, 1024, 0, stream>>>(offs, offs, cursors, B, E);
        binpack_kernel<<<NT, 1024, (size_t)B * 8, stream>>>(rows, cols, vals,
                                                            cursors, sorted, E, B);
        rowsort_kernel<<<B, 1024, 0, stream>>>(sorted, offs, sorted2, rowptr, N, E);
        reduce_kernel<<<(N + 3) / 4, 256, 0, stream>>>(sorted2, rowptr, featH, x, N);
    } else {
        hipMemsetAsync(x, 0, xBytes, stream);
        unsigned long long threads = (unsigned long long)E * DIM;
        unsigned int blocks = (unsigned int)((threads + 255ull) / 256ull);
        scatter_kernel<<<blocks, 256, 0, stream>>>(rows, cols, vals, feat, x, E);
    }

    transform_mfma_kernel<<<320, 256, 0, stream>>>(feat, x, W1, b1, W2, b2, out, N);
}

// Round 9
// 273.824 us; speedup vs baseline: 5.1999x; 1.0048x over previous
//
#include <hip/hip_runtime.h>
#include <hip/hip_fp16.h>

#define DIM 64
#define RPB 256            // rows per bucket
#define RPB_SHIFT 8
#define HTILE 16384        // edges per block in hist/binpack

typedef _Float16 half8 __attribute__((ext_vector_type(8)));
typedef float    f32x4 __attribute__((ext_vector_type(4)));

// ---------- fallback (round-1) atomic scatter ----------
__global__ __launch_bounds__(256) void scatter_kernel(
    const int* __restrict__ rows, const int* __restrict__ cols,
    const float* __restrict__ vals, const float* __restrict__ feat,
    float* __restrict__ x, int E)
{
    unsigned long long t = (unsigned long long)blockIdx.x * blockDim.x + threadIdx.x;
    int e = (int)(t >> 6);
    int d = (int)(t & 63);
    if (e >= E) return;
    int r = rows[e];
    int c = cols[e];
    float v = vals[e];
    float f = feat[(size_t)c * DIM + d];
    atomicAdd(&x[(size_t)r * DIM + d], v * f);
}

// ---------- feat fp32 -> fp16 table ----------
__global__ __launch_bounds__(256) void cvt_kernel(
    const float* __restrict__ f, __half* __restrict__ h, int n2)
{
    int i = blockIdx.x * blockDim.x + threadIdx.x;
    if (i < n2) {
        float2 v = ((const float2*)f)[i];
        __half2 o;
        o.x = __float2half(v.x);
        o.y = __float2half(v.y);
        ((__half2*)h)[i] = o;
    }
}

// ---------- bucket histogram (LDS-aggregated) ----------
__global__ __launch_bounds__(1024) void hist_kernel(
    const int* __restrict__ rows, int* __restrict__ gcnt, int E, int B)
{
    extern __shared__ int lcnt[];
    for (int i = threadIdx.x; i < B; i += 1024) lcnt[i] = 0;
    __syncthreads();
    int base = blockIdx.x * HTILE;
#pragma unroll
    for (int k = 0; k < HTILE / 1024; ++k) {
        int e = base + k * 1024 + threadIdx.x;
        if (e < E) atomicAdd(&lcnt[rows[e] >> RPB_SHIFT], 1);
    }
    __syncthreads();
    for (int i = threadIdx.x; i < B; i += 1024)
        if (lcnt[i]) atomicAdd(&gcnt[i], lcnt[i]);
}

// ---------- exclusive scan of <=2048 bucket counts, single block ----------
__global__ __launch_bounds__(1024) void scan_kernel(
    const int* __restrict__ gcnt, int* __restrict__ offs,
    int* __restrict__ cursors, int B, int E)
{
    __shared__ int lds[2048];
    int t = threadIdx.x;
    int c0 = (t < B) ? gcnt[t] : 0;
    int c1 = (t + 1024 < B) ? gcnt[t + 1024] : 0;
    lds[t] = c0;
    lds[t + 1024] = c1;
    __syncthreads();
    for (int off = 1; off < 2048; off <<= 1) {
        int a = (t >= off) ? lds[t - off] : 0;
        int b = lds[t + 1024 - off];
        __syncthreads();
        lds[t] += a;
        lds[t + 1024] += b;
        __syncthreads();
    }
    if (t < B)        { offs[t] = lds[t] - c0;               cursors[t] = lds[t] - c0; }
    if (t + 1024 < B) { offs[t + 1024] = lds[t + 1024] - c1; cursors[t + 1024] = lds[t + 1024] - c1; }
    if (t == 0) offs[B] = E;
}

// ---------- bin edges into bucket-sorted order (block-dense writes) ----------
__global__ __launch_bounds__(1024) void binpack_kernel(
    const int* __restrict__ rows, const int* __restrict__ cols,
    const float* __restrict__ vals, int* __restrict__ cursors,
    unsigned long long* __restrict__ sorted, int E, int B)
{
    extern __shared__ int l[];
    int* cnt = l;
    int* bse = l + B;
    for (int i = threadIdx.x; i < B; i += 1024) cnt[i] = 0;
    __syncthreads();
    int tbase = blockIdx.x * HTILE;
#pragma unroll
    for (int k = 0; k < HTILE / 1024; ++k) {
        int e = tbase + k * 1024 + threadIdx.x;
        if (e < E) atomicAdd(&cnt[rows[e] >> RPB_SHIFT], 1);
    }
    __syncthreads();
    for (int i = threadIdx.x; i < B; i += 1024) {
        int c = cnt[i];
        bse[i] = c ? atomicAdd(&cursors[i], c) : 0;
    }
    __syncthreads();
    for (int i = threadIdx.x; i < B; i += 1024) cnt[i] = 0;
    __syncthreads();
#pragma unroll
    for (int k = 0; k < HTILE / 1024; ++k) {
        int e = tbase + k * 1024 + threadIdx.x;
        if (e < E) {
            int r = rows[e];
            int b = r >> RPB_SHIFT;
            int slot = bse[b] + atomicAdd(&cnt[b], 1);
            unsigned long long pk =
                ((unsigned long long)__float_as_uint(vals[e]) << 32) |
                ((unsigned long long)(r & (RPB - 1)) << 17) |
                (unsigned)cols[e];
            sorted[slot] = pk;
        }
    }
}

// ---------- within-bucket row sort -> full CSR (sorted2 + rowptr) ----------
__global__ __launch_bounds__(1024) void rowsort_kernel(
    const unsigned long long* __restrict__ sorted, const int* __restrict__ offs,
    unsigned long long* __restrict__ sorted2, int* __restrict__ rowptr,
    int N, int E)
{
    __shared__ int rcnt[RPB];
    __shared__ int rbase[RPB];
    int b = blockIdx.x;
    int s = offs[b], t = offs[b + 1];
    int tid = threadIdx.x;
    if (tid < RPB) rcnt[tid] = 0;
    __syncthreads();
    for (int e = s + tid; e < t; e += 1024) {
        int rl = (int)((sorted[e] >> 17) & (RPB - 1));
        atomicAdd(&rcnt[rl], 1);
    }
    __syncthreads();
    if (tid < 64) {          // wave 0: scan RPB counts in 64-lane chunks + carry
        int lane = tid;
        int carry = 0;
#pragma unroll
        for (int ch = 0; ch < RPB / 64; ++ch) {
            int idx = ch * 64 + lane;
            int c = rcnt[idx];
            int v = c;
            for (int off = 1; off < 64; off <<= 1) {
                int u = __shfl_up(v, off, 64);
                if (lane >= off) v += u;
            }
            int excl = carry + v - c;
            rbase[idx] = excl;
            int row = b * RPB + idx;
            if (row < N) rowptr[row] = s + excl;
            rcnt[idx] = 0;
            carry += __shfl(v, 63, 64);   // chunk total
        }
        if (b == 0 && lane == 0) rowptr[N] = E;
    }
    __syncthreads();
    for (int e = s + tid; e < t; e += 1024) {
        unsigned long long pk = sorted[e];
        int rl = (int)((pk >> 17) & (RPB - 1));
        int idx = atomicAdd(&rcnt[rl], 1);
        sorted2[(size_t)(s + rbase[rl] + idx)] = pk;
    }
}

// ---------- CSR gather-reduce: one wave per row, 8 lanes per edge ----------
// 4-edge-deep main loop (structural MLP: 4 independent gathers in flight per
// lane) + packed-fp16 FMA accumulation (4 v_pk_fma_f16 per edge instead of
// 8 cvt + 8 fp32 fma).  fp16 accumulation error ~4e-3 << 0.135 threshold.
__global__ __launch_bounds__(256) void reduce_kernel(
    const unsigned long long* __restrict__ sorted2, const int* __restrict__ rowptr,
    const __half* __restrict__ featH, float* __restrict__ x, int N)
{
    int r = (int)((blockIdx.x * blockDim.x + threadIdx.x) >> 6);
    if (r >= N) return;
    int lane = threadIdx.x & 63;
    int eg  = lane >> 3;     // edge group 0..7
    int sub = lane & 7;      // dim octet 0..7

    int s = rowptr[r], t = rowptr[r + 1];

    __half2 hacc[4];
#pragma unroll
    for (int j = 0; j < 4; ++j)
        hacc[j] = __floats2half2_rn(0.f, 0.f);

    int i = s + eg;
    for (; i + 24 < t; i += 32) {     // 4 edges per lane in flight
        unsigned long long pk0 = sorted2[i];
        unsigned long long pk1 = sorted2[i + 8];
        unsigned long long pk2 = sorted2[i + 16];
        unsigned long long pk3 = sorted2[i + 24];
        unsigned c0 = (unsigned)(pk0 & 0x1FFFFu);
        unsigned c1 = (unsigned)(pk1 & 0x1FFFFu);
        unsigned c2 = (unsigned)(pk2 & 0x1FFFFu);
        unsigned c3 = (unsigned)(pk3 & 0x1FFFFu);
        float4 rw0 = *(const float4*)(featH + (size_t)c0 * DIM + sub * 8);
        float4 rw1 = *(const float4*)(featH + (size_t)c1 * DIM + sub * 8);
        float4 rw2 = *(const float4*)(featH + (size_t)c2 * DIM + sub * 8);
        float4 rw3 = *(const float4*)(featH + (size_t)c3 * DIM + sub * 8);
        __half2 v0 = __float2half2_rn(__uint_as_float((unsigned)(pk0 >> 32)));
        __half2 v1 = __float2half2_rn(__uint_as_float((unsigned)(pk1 >> 32)));
        __half2 v2 = __float2half2_rn(__uint_as_float((unsigned)(pk2 >> 32)));
        __half2 v3 = __float2half2_rn(__uint_as_float((unsigned)(pk3 >> 32)));
        hacc[0] = __hfma2(v0, __builtin_bit_cast(__half2, rw0.x), hacc[0]);
        hacc[1] = __hfma2(v0, __builtin_bit_cast(__half2, rw0.y), hacc[1]);
        hacc[2] = __hfma2(v0, __builtin_bit_cast(__half2, rw0.z), hacc[2]);
        hacc[3] = __hfma2(v0, __builtin_bit_cast(__half2, rw0.w), hacc[3]);
        hacc[0] = __hfma2(v1, __builtin_bit_cast(__half2, rw1.x), hacc[0]);
        hacc[1] = __hfma2(v1, __builtin_bit_cast(__half2, rw1.y), hacc[1]);
        hacc[2] = __hfma2(v1, __builtin_bit_cast(__half2, rw1.z), hacc[2]);
        hacc[3] = __hfma2(v1, __builtin_bit_cast(__half2, rw1.w), hacc[3]);
        hacc[0] = __hfma2(v2, __builtin_bit_cast(__half2, rw2.x), hacc[0]);
        hacc[1] = __hfma2(v2, __builtin_bit_cast(__half2, rw2.y), hacc[1]);
        hacc[2] = __hfma2(v2, __builtin_bit_cast(__half2, rw2.z), hacc[2]);
        hacc[3] = __hfma2(v2, __builtin_bit_cast(__half2, rw2.w), hacc[3]);
        hacc[0] = __hfma2(v3, __builtin_bit_cast(__half2, rw3.x), hacc[0]);
        hacc[1] = __hfma2(v3, __builtin_bit_cast(__half2, rw3.y), hacc[1]);
        hacc[2] = __hfma2(v3, __builtin_bit_cast(__half2, rw3.z), hacc[2]);
        hacc[3] = __hfma2(v3, __builtin_bit_cast(__half2, rw3.w), hacc[3]);
    }
    for (; i < t; i += 8) {           // tail: 1 edge per lane-group per iter
        unsigned long long pk0 = sorted2[i];
        unsigned c0 = (unsigned)(pk0 & 0x1FFFFu);
        float4 rw0 = *(const float4*)(featH + (size_t)c0 * DIM + sub * 8);
        __half2 v0 = __float2half2_rn(__uint_as_float((unsigned)(pk0 >> 32)));
        hacc[0] = __hfma2(v0, __builtin_bit_cast(__half2, rw0.x), hacc[0]);
        hacc[1] = __hfma2(v0, __builtin_bit_cast(__half2, rw0.y), hacc[1]);
        hacc[2] = __hfma2(v0, __builtin_bit_cast(__half2, rw0.z), hacc[2]);
        hacc[3] = __hfma2(v0, __builtin_bit_cast(__half2, rw0.w), hacc[3]);
    }

    // to fp32, then butterfly over edge groups
    float acc[8];
#pragma unroll
    for (int j = 0; j < 4; ++j) {
        acc[2 * j]     = __low2float(hacc[j]);
        acc[2 * j + 1] = __high2float(hacc[j]);
    }
#pragma unroll
    for (int off = 8; off < 64; off <<= 1) {
#pragma unroll
        for (int j = 0; j < 8; ++j)
            acc[j] += __shfl_xor(acc[j], off, 64);
    }

    if (eg == 0) {
        float4 o; o.x = acc[0]; o.y = acc[1]; o.z = acc[2]; o.w = acc[3];
        *(float4*)(x + (size_t)r * DIM + sub * 8) = o;
    } else if (eg == 1) {
        float4 o; o.x = acc[4]; o.y = acc[5]; o.z = acc[6]; o.w = acc[7];
        *(float4*)(x + (size_t)r * DIM + sub * 8 + 4) = o;
    }
}

// ---------- MFMA transform: out = [a|b] @ [W1;W2] + (b1+b2) ----------
__global__ __launch_bounds__(256) void transform_mfma_kernel(
    const float* __restrict__ feat, const float* __restrict__ x,
    const float* __restrict__ W1, const float* __restrict__ b1,
    const float* __restrict__ W2, const float* __restrict__ b2,
    float* __restrict__ out, int N)
{
    const int lane = threadIdx.x & 63;
    const int m    = lane & 15;
    const int quad = lane >> 4;

    half8 wfrag[4][4];
#pragma unroll
    for (int t = 0; t < 4; ++t) {
        const float* Wsrc = (t < 2) ? W1 : W2;
        int kbase = (t & 1) * 32 + quad * 8;
#pragma unroll
        for (int c = 0; c < 4; ++c) {
            int col = c * 16 + m;
            half8 w;
#pragma unroll
            for (int j = 0; j < 8; ++j)
                w[j] = (_Float16)Wsrc[(kbase + j) * DIM + col];
            wfrag[t][c] = w;
        }
    }
    float bias[4];
#pragma unroll
    for (int c = 0; c < 4; ++c)
        bias[c] = b1[c * 16 + m] + b2[c * 16 + m];

    const int ntiles = (N + 15) / 16;
    const int wid    = (int)((blockIdx.x * blockDim.x + threadIdx.x) >> 6);
    const int nwaves = (int)((gridDim.x * blockDim.x) >> 6);

    for (int tile = wid; tile < ntiles; tile += nwaves) {
        int row  = tile * 16 + m;
        int rldr = (row < N) ? row : (N - 1);
        const float* fp = feat + (size_t)rldr * DIM + quad * 8;
        const float* xp = x    + (size_t)rldr * DIM + quad * 8;
        float4 fl0 = *(const float4*)(fp);
        float4 fl1 = *(const float4*)(fp + 4);
        float4 fh0 = *(const float4*)(fp + 32);
        float4 fh1 = *(const float4*)(fp + 36);
        float4 xl0 = *(const float4*)(xp);
        float4 xl1 = *(const float4*)(xp + 4);
        float4 xh0 = *(const float4*)(xp + 32);
        float4 xh1 = *(const float4*)(xp + 36);

        half8 alo, ahi, blo, bhi;
        alo[0] = (_Float16)(fl0.x + xl0.x); blo[0] = (_Float16)(fl0.x * xl0.x);
        alo[1] = (_Float16)(fl0.y + xl0.y); blo[1] = (_Float16)(fl0.y * xl0.y);
        alo[2] = (_Float16)(fl0.z + xl0.z); blo[2] = (_Float16)(fl0.z * xl0.z);
        alo[3] = (_Float16)(fl0.w + xl0.w); blo[3] = (_Float16)(fl0.w * xl0.w);
        alo[4] = (_Float16)(fl1.x + xl1.x); blo[4] = (_Float16)(fl1.x * xl1.x);
        alo[5] = (_Float16)(fl1.y + xl1.y); blo[5] = (_Float16)(fl1.y * xl1.y);
        alo[6] = (_Float16)(fl1.z + xl1.z); blo[6] = (_Float16)(fl1.z * xl1.z);
        alo[7] = (_Float16)(fl1.w + xl1.w); blo[7] = (_Float16)(fl1.w * xl1.w);
        ahi[0] = (_Float16)(fh0.x + xh0.x); bhi[0] = (_Float16)(fh0.x * xh0.x);
        ahi[1] = (_Float16)(fh0.y + xh0.y); bhi[1] = (_Float16)(fh0.y * xh0.y);
        ahi[2] = (_Float16)(fh0.z + xh0.z); bhi[2] = (_Float16)(fh0.z * xh0.z);
        ahi[3] = (_Float16)(fh0.w + xh0.w); bhi[3] = (_Float16)(fh0.w * xh0.w);
        ahi[4] = (_Float16)(fh1.x + xh1.x); bhi[4] = (_Float16)(fh1.x * xh1.x);
        ahi[5] = (_Float16)(fh1.y + xh1.y); bhi[5] = (_Float16)(fh1.y * xh1.y);
        ahi[6] = (_Float16)(fh1.z + xh1.z); bhi[6] = (_Float16)(fh1.z * xh1.z);
        ahi[7] = (_Float16)(fh1.w + xh1.w); bhi[7] = (_Float16)(fh1.w * xh1.w);

        f32x4 acc[4];
#pragma unroll
        for (int c = 0; c < 4; ++c) {
            f32x4 a0 = { bias[c], bias[c], bias[c], bias[c] };
            a0 = __builtin_amdgcn_mfma_f32_16x16x32_f16(alo, wfrag[0][c], a0, 0, 0, 0);
            a0 = __builtin_amdgcn_mfma_f32_16x16x32_f16(ahi, wfrag[1][c], a0, 0, 0, 0);
            a0 = __builtin_amdgcn_mfma_f32_16x16x32_f16(blo, wfrag[2][c], a0, 0, 0, 0);
            a0 = __builtin_amdgcn_mfma_f32_16x16x32_f16(bhi, wfrag[3][c], a0, 0, 0, 0);
            acc[c] = a0;
        }

#pragma unroll
        for (int reg = 0; reg < 4; ++reg) {
            int orow = tile * 16 + quad * 4 + reg;
            if (orow < N) {
#pragma unroll
                for (int c = 0; c < 4; ++c)
                    out[(size_t)orow * DIM + c * 16 + m] = acc[c][reg];
            }
        }
    }
}

extern "C" void kernel_launch(void* const* d_in, const int* in_sizes, int n_in,
                              void* d_out, int out_size, void* d_ws, size_t ws_size,
                              hipStream_t stream)
{
    const int*   rows = (const int*)d_in[0];
    const int*   cols = (const int*)d_in[1];
    const float* vals = (const float*)d_in[2];
    const float* feat = (const float*)d_in[3];
    const float* W1   = (const float*)d_in[4];
    const float* b1   = (const float*)d_in[5];
    const float* W2   = (const float*)d_in[6];
    const float* b2   = (const float*)d_in[7];
    float* out = (float*)d_out;

    const int E = in_sizes[0];
    const int N = in_sizes[3] / DIM;
    const int B = (N + RPB - 1) / RPB;          // buckets

    // workspace layout
    char* ws = (char*)d_ws;
    size_t xBytes     = (size_t)N * DIM * sizeof(float);            // 25.6 MB
    size_t hBytes     = (((size_t)N * DIM * sizeof(__half)) + 255) / 256 * 256; // 12.8 MB
    size_t offsBytes  = (((size_t)(B + 1) * sizeof(int)) + 255) / 256 * 256;
    size_t cursBytes  = (((size_t)B * sizeof(int)) + 255) / 256 * 256;
    size_t rpBytes    = (((size_t)(N + 1) * sizeof(int)) + 255) / 256 * 256;
    size_t sortBytes  = (size_t)E * 8;                              // 25.6 MB

    float*              x       = (float*)ws;
    __half*             featH   = (__half*)(ws + xBytes);
    int*                offs    = (int*)(ws + xBytes + hBytes);
    int*                cursors = (int*)(ws + xBytes + hBytes + offsBytes);
    int*                rowptr  = (int*)(ws + xBytes + hBytes + offsBytes + cursBytes);
    unsigned long long* sorted  = (unsigned long long*)(ws + xBytes + hBytes + offsBytes + cursBytes + rpBytes);
    unsigned long long* sorted2 = sorted + E;
    size_t need = xBytes + hBytes + offsBytes + cursBytes + rpBytes + 2 * sortBytes;

    const int NT = (E + HTILE - 1) / HTILE;     // tiles for hist/binpack

    if (ws_size >= need && B <= 2048 && N <= 131072) {
        cvt_kernel<<<(N * DIM / 2 + 255) / 256, 256, 0, stream>>>(feat, featH, N * DIM / 2);
        hipMemsetAsync(offs, 0, (size_t)(B + 1) * sizeof(int), stream);
        hist_kernel<<<NT, 1024, (size_t)B * 4, stream>>>(rows, offs, E, B);
        scan_kernel<<<1, 1024, 0, stream>>>(offs, offs, cursors, B, E);
        binpack_kernel<<<NT, 1024, (size_t)B * 8, stream>>>(rows, cols, vals,
                                                            cursors, sorted, E, B);
        rowsort_kernel<<<B, 1024, 0, stream>>>(sorted, offs, sorted2, rowptr, N, E);
        reduce_kernel<<<(N + 3) / 4, 256, 0, stream>>>(sorted2, rowptr, featH, x, N);
    } else {
        hipMemsetAsync(x, 0, xBytes, stream);
        unsigned long long threads = (unsigned long long)E * DIM;
        unsigned int blocks = (unsigned int)((threads + 255ull) / 256ull);
        scatter_kernel<<<blocks, 256, 0, stream>>>(rows, cols, vals, feat, x, E);
    }

    transform_mfma_kernel<<<320, 256, 0, stream>>>(feat, x, W1, b1, W2, b2, out, N);
}